// Round 1
// baseline (1755.854 us; speedup 1.0000x reference)
//
#include <hip/hip_runtime.h>

// Conv1D dequant-GEMM: y[M,N] = x[M,K] @ (w_q[K,N]*scale[N]) + bias[N]
// M=8192 (B*S), K=4096, N=16384. fp32 I/O, int8-valued int32 weights.
// bf16 MFMA (w_q exact in bf16; scale/bias applied in fp32 epilogue).
// GEMM = 256x256 tile, BK=64, 8-wave, 8-phase counted-vmcnt schedule
// (T1 XCD-swizzle + T2 LDS XOR-swizzle + T3/T4 phase pipeline + T5 setprio).

#define M_DIM 8192
#define K_DIM 4096
#define N_DIM 16384

#define BM 256
#define BN 256
#define BK 64
#define NT (K_DIM / BK)          // 64 K-tiles
#define NWG ((M_DIM / BM) * (N_DIM / BN))   // 32*64 = 2048 blocks

typedef unsigned short u16;
typedef __attribute__((ext_vector_type(8))) short short8;   // 8 x bf16 bits
typedef __attribute__((ext_vector_type(4))) float floatx4;  // MFMA acc

__device__ __forceinline__ u16 f2bf(float f) {
    unsigned int u = __builtin_bit_cast(unsigned int, f);
    u += 0x7fffu + ((u >> 16) & 1u);
    return (u16)(u >> 16);
}

// ---------------- prep 1: x fp32 -> bf16 (verified) ----------------
__global__ __launch_bounds__(256) void cvt_x_kernel(const float4* __restrict__ x,
                                                    uint4* __restrict__ out) {
    int i = blockIdx.x * 256 + threadIdx.x;
    float4 a = x[2 * i];
    float4 b = x[2 * i + 1];
    uint4 o;
    o.x = (unsigned)f2bf(a.x) | ((unsigned)f2bf(a.y) << 16);
    o.y = (unsigned)f2bf(a.z) | ((unsigned)f2bf(a.w) << 16);
    o.z = (unsigned)f2bf(b.x) | ((unsigned)f2bf(b.y) << 16);
    o.w = (unsigned)f2bf(b.z) | ((unsigned)f2bf(b.w) << 16);
    out[i] = o;
}

// ---------------- prep 2: w_q[K,N] int32 -> wT[N,K] bf16 (verified) ----
__global__ __launch_bounds__(256) void transpose_wq(const int* __restrict__ wq,
                                                    u16* __restrict__ wT) {
    __shared__ u16 tile[64][65];
    const int n0 = blockIdx.x * 64;
    const int k0 = blockIdx.y * 64;
    const int tx = threadIdx.x;
    const int ty = threadIdx.y;
    #pragma unroll
    for (int r = 0; r < 4; ++r) {
        int kl = ty + 16 * r;
        const int4 v = *(const int4*)(wq + (size_t)(k0 + kl) * N_DIM + n0 + tx * 4);
        tile[kl][tx * 4 + 0] = f2bf((float)v.x);
        tile[kl][tx * 4 + 1] = f2bf((float)v.y);
        tile[kl][tx * 4 + 2] = f2bf((float)v.z);
        tile[kl][tx * 4 + 3] = f2bf((float)v.w);
    }
    __syncthreads();
    #pragma unroll
    for (int r = 0; r < 4; ++r) {
        int nl = ty + 16 * r;
        ushort4 o;
        o.x = tile[tx * 4 + 0][nl];
        o.y = tile[tx * 4 + 1][nl];
        o.z = tile[tx * 4 + 2][nl];
        o.w = tile[tx * 4 + 3][nl];
        *(ushort4*)(wT + (size_t)(n0 + nl) * K_DIM + k0 + tx * 4) = o;
    }
}

// ---------------- async global->LDS 16B ----------------
__device__ __forceinline__ void async_copy16(const u16* gptr, u16* ldsptr) {
    __builtin_amdgcn_global_load_lds(
        (const __attribute__((address_space(1))) void*)gptr,
        (__attribute__((address_space(3))) void*)ldsptr,
        16, 0, 0);
}

// ---------------- main GEMM: 256x256 tile, 8-phase schedule ----------------
// LDS map (u16 units): buf p in {0,1} at p*32768.
//   A halves: p*32768 + h*8192          (h = row/128), [128][64] each
//   B halves: p*32768 + 16384 + h*8192
// XOR swizzle: 16B-slot s of row r stored at slot s^(r&7) (applied on the
// GLOBAL source address; LDS dest stays linear for global_load_lds), and the
// same XOR applied on the ds_read side. 16-way bank conflict -> 2-way (free).
__global__ __launch_bounds__(512, 2) void gemm_bf16(const u16* __restrict__ A,
                                                    const u16* __restrict__ Bt,
                                                    const float* __restrict__ scale,
                                                    const float* __restrict__ bias,
                                                    float* __restrict__ C) {
    __shared__ u16 smem[65536];  // 128 KiB

    const int tid  = threadIdx.x;
    const int lane = tid & 63;
    const int wave = tid >> 6;
    const int wr   = wave >> 2;      // 0..1 : wave row (128 rows each)
    const int wc   = wave & 3;       // 0..3 : wave col (64 cols each)
    const int fr   = lane & 15;
    const int quad = lane >> 4;

    // T1: bijective XCD swizzle (2048 % 8 == 0) + GROUP_M=8 decomposition
    int wg = blockIdx.x;
    wg = (wg & 7) * (NWG / 8) + (wg >> 3);
    const int grp = wg >> 9;                 // / (8*64)
    const int rem = wg & 511;
    const int by  = grp * 8 + (rem & 7);     // 0..31
    const int bx  = rem >> 3;                // 0..63
    const int m0 = by * BM;
    const int n0 = bx * BN;

    // fragment-read offsets (u16): row (i*16+fr) within half, k-slot swizzled
    const int sw   = fr & 7;
    const int sl0  = (quad ^ sw) * 8;        // ks=0 16B-slot, swizzled
    const int sl1  = sl0 ^ 32;               // ks=1 slot = slot0^4 -> *8 = ^32
    const int rA   = fr * 64;
    const int aBase0 = wr * 8192;                                  // this wave's A half
    const int bBase0 = 16384 + (wc >> 1) * 8192 + (wc & 1) * 4096; // B half + 64-row sub

    // staging coords: thread stages 16B chunks c=tid and c=tid+512 per half-tile
    const int srow  = tid >> 3;                        // 0..63 (and +64)
    const int sslot = ((tid & 7) ^ (srow & 7)) * 8;    // inverse-swizzled source slot
    const int ldst  = tid * 8;                         // linear LDS dest (u16)

#define STAGE_A(t_, h_, p_) do {                                               \
    const u16* g_ = A + (size_t)(m0 + (h_) * 128 + srow) * K_DIM + (t_) * BK + sslot; \
    u16* l_ = smem + (p_) * 32768 + (h_) * 8192 + ldst;                        \
    async_copy16(g_, l_);                                                      \
    async_copy16(g_ + (size_t)64 * K_DIM, l_ + 4096);                          \
} while (0)

#define STAGE_B(t_, h_, p_) do {                                               \
    const u16* g_ = Bt + (size_t)(n0 + (h_) * 128 + srow) * K_DIM + (t_) * BK + sslot; \
    u16* l_ = smem + (p_) * 32768 + 16384 + (h_) * 8192 + ldst;                \
    async_copy16(g_, l_);                                                      \
    async_copy16(g_ + (size_t)64 * K_DIM, l_ + 4096);                          \
} while (0)

    floatx4 acc[8][4];
    #pragma unroll
    for (int i = 0; i < 8; ++i)
        #pragma unroll
        for (int j = 0; j < 4; ++j)
            acc[i][j] = (floatx4){0.f, 0.f, 0.f, 0.f};

    // prologue: stage tiles 0 and 1; retire tile 0, keep tile 1 in flight
    STAGE_A(0, 0, 0); STAGE_A(0, 1, 0); STAGE_B(0, 0, 0); STAGE_B(0, 1, 0);
    STAGE_A(1, 0, 1); STAGE_A(1, 1, 1); STAGE_B(1, 0, 1); STAGE_B(1, 1, 1);
    asm volatile("s_waitcnt vmcnt(8)" ::: "memory");
    __builtin_amdgcn_s_barrier();
    __builtin_amdgcn_sched_barrier(0);

    short8 af[4][2], bfv[4][2];

    for (int t = 0; t < NT; ++t) {
        const int p = t & 1;
        const u16* SA = smem + p * 32768 + aBase0;
        const u16* SB = smem + p * 32768 + bBase0;

        // ---- phase 1: ds A i0-3 + B j0-1 ; MFMA Q(0,0) ----
        #pragma unroll
        for (int i = 0; i < 4; ++i) {
            af[i][0] = *(const short8*)(SA + i * 1024 + rA + sl0);
            af[i][1] = *(const short8*)(SA + i * 1024 + rA + sl1);
        }
        #pragma unroll
        for (int j = 0; j < 2; ++j) {
            bfv[j][0] = *(const short8*)(SB + j * 1024 + rA + sl0);
            bfv[j][1] = *(const short8*)(SB + j * 1024 + rA + sl1);
        }
        __builtin_amdgcn_s_barrier();
        asm volatile("s_waitcnt lgkmcnt(0)" ::: "memory");
        __builtin_amdgcn_s_setprio(1);
        #pragma unroll
        for (int i = 0; i < 4; ++i)
            #pragma unroll
            for (int j = 0; j < 2; ++j) {
                acc[i][j] = __builtin_amdgcn_mfma_f32_16x16x32_bf16(af[i][0], bfv[j][0], acc[i][j], 0, 0, 0);
                acc[i][j] = __builtin_amdgcn_mfma_f32_16x16x32_bf16(af[i][1], bfv[j][1], acc[i][j], 0, 0, 0);
            }
        __builtin_amdgcn_s_setprio(0);
        __builtin_amdgcn_s_barrier();
        __builtin_amdgcn_sched_barrier(0);

        // ---- phase 2: ds B j2-3 ; MFMA Q(0,1) ----
        #pragma unroll
        for (int j = 2; j < 4; ++j) {
            bfv[j][0] = *(const short8*)(SB + j * 1024 + rA + sl0);
            bfv[j][1] = *(const short8*)(SB + j * 1024 + rA + sl1);
        }
        __builtin_amdgcn_s_barrier();
        asm volatile("s_waitcnt lgkmcnt(0)" ::: "memory");
        __builtin_amdgcn_s_setprio(1);
        #pragma unroll
        for (int i = 0; i < 4; ++i)
            #pragma unroll
            for (int j = 2; j < 4; ++j) {
                acc[i][j] = __builtin_amdgcn_mfma_f32_16x16x32_bf16(af[i][0], bfv[j][0], acc[i][j], 0, 0, 0);
                acc[i][j] = __builtin_amdgcn_mfma_f32_16x16x32_bf16(af[i][1], bfv[j][1], acc[i][j], 0, 0, 0);
            }
        __builtin_amdgcn_s_setprio(0);
        __builtin_amdgcn_s_barrier();
        __builtin_amdgcn_sched_barrier(0);

        // ---- phase 3: ds A i4-7 ; stage B(t+2) into buf p ; MFMA Q(1,0) ----
        // (tile t's B-reads all executed by phase-2's closing barrier -> B slots free)
        #pragma unroll
        for (int i = 0; i < 4; ++i) {
            af[i][0] = *(const short8*)(SA + (i + 4) * 1024 + rA + sl0);
            af[i][1] = *(const short8*)(SA + (i + 4) * 1024 + rA + sl1);
        }
        if (t < NT - 2) { STAGE_B(t + 2, 0, p); STAGE_B(t + 2, 1, p); }
        __builtin_amdgcn_s_barrier();
        asm volatile("s_waitcnt lgkmcnt(0)" ::: "memory");
        __builtin_amdgcn_s_setprio(1);
        #pragma unroll
        for (int i = 0; i < 4; ++i)
            #pragma unroll
            for (int j = 0; j < 2; ++j) {
                acc[i + 4][j] = __builtin_amdgcn_mfma_f32_16x16x32_bf16(af[i][0], bfv[j][0], acc[i + 4][j], 0, 0, 0);
                acc[i + 4][j] = __builtin_amdgcn_mfma_f32_16x16x32_bf16(af[i][1], bfv[j][1], acc[i + 4][j], 0, 0, 0);
            }
        __builtin_amdgcn_s_setprio(0);
        __builtin_amdgcn_s_barrier();
        __builtin_amdgcn_sched_barrier(0);

        // ---- phase 4: stage A(t+2) into buf p ; MFMA Q(1,1) ; counted vmcnt ----
        // (tile t's A-reads all executed by phase-3's closing barrier -> A slots free)
        if (t < NT - 2) { STAGE_A(t + 2, 0, p); STAGE_A(t + 2, 1, p); }
        __builtin_amdgcn_s_barrier();
        __builtin_amdgcn_s_setprio(1);
        #pragma unroll
        for (int i = 0; i < 4; ++i)
            #pragma unroll
            for (int j = 2; j < 4; ++j) {
                acc[i + 4][j] = __builtin_amdgcn_mfma_f32_16x16x32_bf16(af[i][0], bfv[j][0], acc[i + 4][j], 0, 0, 0);
                acc[i + 4][j] = __builtin_amdgcn_mfma_f32_16x16x32_bf16(af[i][1], bfv[j][1], acc[i + 4][j], 0, 0, 0);
            }
        __builtin_amdgcn_s_setprio(0);
        // retire tile t+1 (8 oldest loads); keep tile t+2's 8 loads in flight.
        if (t < NT - 2) {
            asm volatile("s_waitcnt vmcnt(8)" ::: "memory");
        } else if (t == NT - 2) {
            asm volatile("s_waitcnt vmcnt(0)" ::: "memory");
        }
        __builtin_amdgcn_s_barrier();
        __builtin_amdgcn_sched_barrier(0);
    }

    // epilogue: y = acc*scale[col] + bias[col]; C/D map col=lane&15, row=quad*4+r
    #pragma unroll
    for (int j = 0; j < 4; ++j) {
        const int col = n0 + wc * 64 + j * 16 + fr;
        const float s = scale[col];
        const float b = bias[col];
        #pragma unroll
        for (int i = 0; i < 8; ++i) {
            const int rowb = m0 + wr * 128 + i * 16 + quad * 4;
            #pragma unroll
            for (int r = 0; r < 4; ++r)
                C[(size_t)(rowb + r) * N_DIM + col] = acc[i][j][r] * s + b;
        }
    }
#undef STAGE_A
#undef STAGE_B
}

extern "C" void kernel_launch(void* const* d_in, const int* in_sizes, int n_in,
                              void* d_out, int out_size, void* d_ws, size_t ws_size,
                              hipStream_t stream) {
    const float* x     = (const float*)d_in[0];
    const int*   wq    = (const int*)d_in[1];
    const float* scale = (const float*)d_in[2];
    const float* bias  = (const float*)d_in[3];
    float* y = (float*)d_out;

    u16* wT = (u16*)d_ws;                                        // 128 MiB
    u16* xb = (u16*)((char*)d_ws + (size_t)N_DIM * K_DIM * 2);   // +64 MiB

    cvt_x_kernel<<<(M_DIM * (size_t)K_DIM) / (256 * 8), 256, 0, stream>>>(
        (const float4*)x, (uint4*)xb);
    transpose_wq<<<dim3(N_DIM / 64, K_DIM / 64), dim3(16, 16), 0, stream>>>(wq, wT);
    gemm_bf16<<<dim3(NWG), 512, 0, stream>>>(xb, wT, scale, bias, y);
}

// Round 2
// 1715.011 us; speedup vs baseline: 1.0238x; 1.0238x over previous
//
#include <hip/hip_runtime.h>

// Conv1D dequant-GEMM: y[M,N] = x[M,K] @ (w_q[K,N]*scale[N]) + bias[N]
// M=8192 (B*S), K=4096, N=16384. fp32 I/O, int8-valued int32 weights.
// bf16 MFMA (w_q exact in bf16; scale/bias applied in fp32 epilogue).
// GEMM = 256x256 tile, BK=64, 8-wave, balanced 4-phase counted-vmcnt schedule
// (T1 XCD-swizzle + T2 LDS XOR-swizzle + T3/T4 phase pipeline + T5 setprio).
// R1->R2: phases re-split by (i-half, kk): ds_reads 12/4/8/0 -> 8/4/8/4,
// staging moved to ph1 (A next tile) / ph4 (B tile+2), vmcnt(4) per tile.

#define M_DIM 8192
#define K_DIM 4096
#define N_DIM 16384

#define BM 256
#define BN 256
#define BK 64
#define NT (K_DIM / BK)          // 64 K-tiles
#define NWG ((M_DIM / BM) * (N_DIM / BN))   // 32*64 = 2048 blocks

typedef unsigned short u16;
typedef __attribute__((ext_vector_type(8))) short short8;   // 8 x bf16 bits
typedef __attribute__((ext_vector_type(4))) float floatx4;  // MFMA acc

__device__ __forceinline__ u16 f2bf(float f) {
    unsigned int u = __builtin_bit_cast(unsigned int, f);
    u += 0x7fffu + ((u >> 16) & 1u);
    return (u16)(u >> 16);
}

// ---------------- prep 1: x fp32 -> bf16 (verified) ----------------
__global__ __launch_bounds__(256) void cvt_x_kernel(const float4* __restrict__ x,
                                                    uint4* __restrict__ out) {
    int i = blockIdx.x * 256 + threadIdx.x;
    float4 a = x[2 * i];
    float4 b = x[2 * i + 1];
    uint4 o;
    o.x = (unsigned)f2bf(a.x) | ((unsigned)f2bf(a.y) << 16);
    o.y = (unsigned)f2bf(a.z) | ((unsigned)f2bf(a.w) << 16);
    o.z = (unsigned)f2bf(b.x) | ((unsigned)f2bf(b.y) << 16);
    o.w = (unsigned)f2bf(b.z) | ((unsigned)f2bf(b.w) << 16);
    out[i] = o;
}

// ---------------- prep 2: w_q[K,N] int32 -> wT[N,K] bf16 (verified) ----
__global__ __launch_bounds__(256) void transpose_wq(const int* __restrict__ wq,
                                                    u16* __restrict__ wT) {
    __shared__ u16 tile[64][65];
    const int n0 = blockIdx.x * 64;
    const int k0 = blockIdx.y * 64;
    const int tx = threadIdx.x;
    const int ty = threadIdx.y;
    #pragma unroll
    for (int r = 0; r < 4; ++r) {
        int kl = ty + 16 * r;
        const int4 v = *(const int4*)(wq + (size_t)(k0 + kl) * N_DIM + n0 + tx * 4);
        tile[kl][tx * 4 + 0] = f2bf((float)v.x);
        tile[kl][tx * 4 + 1] = f2bf((float)v.y);
        tile[kl][tx * 4 + 2] = f2bf((float)v.z);
        tile[kl][tx * 4 + 3] = f2bf((float)v.w);
    }
    __syncthreads();
    #pragma unroll
    for (int r = 0; r < 4; ++r) {
        int nl = ty + 16 * r;
        ushort4 o;
        o.x = tile[tx * 4 + 0][nl];
        o.y = tile[tx * 4 + 1][nl];
        o.z = tile[tx * 4 + 2][nl];
        o.w = tile[tx * 4 + 3][nl];
        *(ushort4*)(wT + (size_t)(n0 + nl) * K_DIM + k0 + tx * 4) = o;
    }
}

// ---------------- async global->LDS 16B ----------------
__device__ __forceinline__ void async_copy16(const u16* gptr, u16* ldsptr) {
    __builtin_amdgcn_global_load_lds(
        (const __attribute__((address_space(1))) void*)gptr,
        (__attribute__((address_space(3))) void*)ldsptr,
        16, 0, 0);
}

// ---------------- main GEMM: 256x256 tile, balanced 4-phase schedule -------
// LDS map (u16 units): buf p in {0,1} at p*32768.
//   A halves: p*32768 + h*8192          (h = row/128), [128][64] each
//   B halves: p*32768 + 16384 + h*8192
// XOR swizzle: 16B-slot s of row r stored at slot s^(r&7) (applied on the
// GLOBAL source address; LDS dest stays linear for global_load_lds), and the
// same XOR applied on the ds_read side. 16-way bank conflict -> 2-way (free).
__global__ __launch_bounds__(512, 2) void gemm_bf16(const u16* __restrict__ A,
                                                    const u16* __restrict__ Bt,
                                                    const float* __restrict__ scale,
                                                    const float* __restrict__ bias,
                                                    float* __restrict__ C) {
    __shared__ u16 smem[65536];  // 128 KiB

    const int tid  = threadIdx.x;
    const int lane = tid & 63;
    const int wave = tid >> 6;
    const int wr   = wave >> 2;      // 0..1 : wave row (128 rows each)
    const int wc   = wave & 3;       // 0..3 : wave col (64 cols each)
    const int fr   = lane & 15;
    const int quad = lane >> 4;

    // T1: bijective XCD swizzle (2048 % 8 == 0) + GROUP_M=8 decomposition
    int wg = blockIdx.x;
    wg = (wg & 7) * (NWG / 8) + (wg >> 3);
    const int grp = wg >> 9;                 // / (8*64)
    const int rem = wg & 511;
    const int by  = grp * 8 + (rem & 7);     // 0..31
    const int bx  = rem >> 3;                // 0..63
    const int m0 = by * BM;
    const int n0 = bx * BN;

    // fragment-read offsets (u16): row (i*16+fr) within half, k-slot swizzled
    const int sw   = fr & 7;
    const int sl0  = (quad ^ sw) * 8;        // kk=0 16B-slot, swizzled
    const int sl1  = sl0 ^ 32;               // kk=1 slot = slot0^4 -> *8 = ^32
    const int rA   = fr * 64;
    const int aBase0 = wr * 8192;                                  // this wave's A half
    const int bBase0 = 16384 + (wc >> 1) * 8192 + (wc & 1) * 4096; // B half + 64-row sub

    // staging coords: thread stages 16B chunks c=tid and c=tid+512 per half-tile
    const int srow  = tid >> 3;                        // 0..63 (and +64)
    const int sslot = ((tid & 7) ^ (srow & 7)) * 8;    // inverse-swizzled source slot
    const int ldst  = tid * 8;                         // linear LDS dest (u16)

#define STAGE_A(t_, h_, p_) do {                                               \
    const u16* g_ = A + (size_t)(m0 + (h_) * 128 + srow) * K_DIM + (t_) * BK + sslot; \
    u16* l_ = smem + (p_) * 32768 + (h_) * 8192 + ldst;                        \
    async_copy16(g_, l_);                                                      \
    async_copy16(g_ + (size_t)64 * K_DIM, l_ + 4096);                          \
} while (0)

#define STAGE_B(t_, h_, p_) do {                                               \
    const u16* g_ = Bt + (size_t)(n0 + (h_) * 128 + srow) * K_DIM + (t_) * BK + sslot; \
    u16* l_ = smem + (p_) * 32768 + 16384 + (h_) * 8192 + ldst;                \
    async_copy16(g_, l_);                                                      \
    async_copy16(g_ + (size_t)64 * K_DIM, l_ + 4096);                          \
} while (0)

    floatx4 acc[8][4];
    #pragma unroll
    for (int i = 0; i < 8; ++i)
        #pragma unroll
        for (int j = 0; j < 4; ++j)
            acc[i][j] = (floatx4){0.f, 0.f, 0.f, 0.f};

    // prologue: stage tile 0 (A+B) and tile 1 (B only; A(1) staged in iter0 ph1)
    STAGE_A(0, 0, 0); STAGE_A(0, 1, 0); STAGE_B(0, 0, 0); STAGE_B(0, 1, 0);
    STAGE_B(1, 0, 1); STAGE_B(1, 1, 1);
    asm volatile("s_waitcnt vmcnt(4)" ::: "memory");   // tile 0 landed, B(1) in flight
    __builtin_amdgcn_s_barrier();
    __builtin_amdgcn_sched_barrier(0);

    short8 af[4], bfv[4];

    for (int t = 0; t < NT; ++t) {
        const int p  = t & 1;
        const int pn = p ^ 1;
        const u16* SA = smem + p * 32768 + aBase0;
        const u16* SB = smem + p * 32768 + bBase0;

        // ---- phase 1: ds A i0-3 k0 + B j0-3 k0 ; stage A(t+1)->buf pn ;
        //               MFMA (i0-3 x j0-3, k0) ----
        // (A(t+1) write to buf pn legal: tile t-1's A-reads done at iter t-1
        //  phase-4 closing barrier)
        #pragma unroll
        for (int i = 0; i < 4; ++i)
            af[i] = *(const short8*)(SA + i * 1024 + rA + sl0);
        #pragma unroll
        for (int j = 0; j < 4; ++j)
            bfv[j] = *(const short8*)(SB + j * 1024 + rA + sl0);
        if (t + 1 < NT) { STAGE_A(t + 1, 0, pn); STAGE_A(t + 1, 1, pn); }
        __builtin_amdgcn_s_barrier();
        asm volatile("s_waitcnt lgkmcnt(0)" ::: "memory");
        __builtin_amdgcn_s_setprio(1);
        #pragma unroll
        for (int i = 0; i < 4; ++i)
            #pragma unroll
            for (int j = 0; j < 4; ++j)
                acc[i][j] = __builtin_amdgcn_mfma_f32_16x16x32_bf16(af[i], bfv[j], acc[i][j], 0, 0, 0);
        __builtin_amdgcn_s_setprio(0);
        __builtin_amdgcn_s_barrier();
        __builtin_amdgcn_sched_barrier(0);

        // ---- phase 2: ds A i4-7 k0 ; MFMA (i4-7 x j0-3, k0) ----
        #pragma unroll
        for (int i = 0; i < 4; ++i)
            af[i] = *(const short8*)(SA + (i + 4) * 1024 + rA + sl0);
        __builtin_amdgcn_s_barrier();
        asm volatile("s_waitcnt lgkmcnt(0)" ::: "memory");
        __builtin_amdgcn_s_setprio(1);
        #pragma unroll
        for (int i = 0; i < 4; ++i)
            #pragma unroll
            for (int j = 0; j < 4; ++j)
                acc[i + 4][j] = __builtin_amdgcn_mfma_f32_16x16x32_bf16(af[i], bfv[j], acc[i + 4][j], 0, 0, 0);
        __builtin_amdgcn_s_setprio(0);
        __builtin_amdgcn_s_barrier();
        __builtin_amdgcn_sched_barrier(0);

        // ---- phase 3: ds A i0-3 k1 + B j0-3 k1 ; MFMA (i0-3 x j0-3, k1) ----
        #pragma unroll
        for (int i = 0; i < 4; ++i)
            af[i] = *(const short8*)(SA + i * 1024 + rA + sl1);
        #pragma unroll
        for (int j = 0; j < 4; ++j)
            bfv[j] = *(const short8*)(SB + j * 1024 + rA + sl1);
        __builtin_amdgcn_s_barrier();
        asm volatile("s_waitcnt lgkmcnt(0)" ::: "memory");
        __builtin_amdgcn_s_setprio(1);
        #pragma unroll
        for (int i = 0; i < 4; ++i)
            #pragma unroll
            for (int j = 0; j < 4; ++j)
                acc[i][j] = __builtin_amdgcn_mfma_f32_16x16x32_bf16(af[i], bfv[j], acc[i][j], 0, 0, 0);
        __builtin_amdgcn_s_setprio(0);
        __builtin_amdgcn_s_barrier();
        __builtin_amdgcn_sched_barrier(0);

        // ---- phase 4: ds A i4-7 k1 ; stage B(t+2)->buf p ; MFMA (i4-7 x j, k1);
        //               counted vmcnt ----
        // (B(t+2) write to buf p legal: tile t's B k1-reads done at phase-3
        //  closing barrier)
        #pragma unroll
        for (int i = 0; i < 4; ++i)
            af[i] = *(const short8*)(SA + (i + 4) * 1024 + rA + sl1);
        if (t + 2 < NT) { STAGE_B(t + 2, 0, p); STAGE_B(t + 2, 1, p); }
        __builtin_amdgcn_s_barrier();
        asm volatile("s_waitcnt lgkmcnt(0)" ::: "memory");
        __builtin_amdgcn_s_setprio(1);
        #pragma unroll
        for (int i = 0; i < 4; ++i)
            #pragma unroll
            for (int j = 0; j < 4; ++j)
                acc[i + 4][j] = __builtin_amdgcn_mfma_f32_16x16x32_bf16(af[i], bfv[j], acc[i + 4][j], 0, 0, 0);
        __builtin_amdgcn_s_setprio(0);
        // retire next tile's loads (A(t+1) + B(t+1)); keep B(t+2) in flight
        if (t < NT - 2) {
            asm volatile("s_waitcnt vmcnt(4)" ::: "memory");
        } else if (t == NT - 2) {
            asm volatile("s_waitcnt vmcnt(0)" ::: "memory");
        }
        __builtin_amdgcn_s_barrier();
        __builtin_amdgcn_sched_barrier(0);
    }

    // epilogue: y = acc*scale[col] + bias[col]; C/D map col=lane&15, row=quad*4+r
    #pragma unroll
    for (int j = 0; j < 4; ++j) {
        const int col = n0 + wc * 64 + j * 16 + fr;
        const float s = scale[col];
        const float b = bias[col];
        #pragma unroll
        for (int i = 0; i < 8; ++i) {
            const int rowb = m0 + wr * 128 + i * 16 + quad * 4;
            #pragma unroll
            for (int r = 0; r < 4; ++r)
                C[(size_t)(rowb + r) * N_DIM + col] = acc[i][j][r] * s + b;
        }
    }
#undef STAGE_A
#undef STAGE_B
}

extern "C" void kernel_launch(void* const* d_in, const int* in_sizes, int n_in,
                              void* d_out, int out_size, void* d_ws, size_t ws_size,
                              hipStream_t stream) {
    const float* x     = (const float*)d_in[0];
    const int*   wq    = (const int*)d_in[1];
    const float* scale = (const float*)d_in[2];
    const float* bias  = (const float*)d_in[3];
    float* y = (float*)d_out;

    u16* wT = (u16*)d_ws;                                        // 128 MiB
    u16* xb = (u16*)((char*)d_ws + (size_t)N_DIM * K_DIM * 2);   // +64 MiB

    cvt_x_kernel<<<(M_DIM * (size_t)K_DIM) / (256 * 8), 256, 0, stream>>>(
        (const float4*)x, (uint4*)xb);
    transpose_wq<<<dim3(N_DIM / 64, K_DIM / 64), dim3(16, 16), 0, stream>>>(wq, wT);
    gemm_bf16<<<dim3(NWG), 512, 0, stream>>>(xb, wT, scale, bias, y);
}

// Round 3
// 1667.293 us; speedup vs baseline: 1.0531x; 1.0286x over previous
//
#include <hip/hip_runtime.h>

// Conv1D dequant-GEMM: y[M,N] = x[M,K] @ (w_q[K,N]*scale[N]) + bias[N]
// M=8192 (B*S), K=4096, N=16384. fp32 I/O, int8-valued int32 weights.
// bf16 MFMA (w_q exact in bf16; scale/bias applied in fp32 epilogue).
// GEMM = 256x256 tile, BK=64, 8-wave. R2->R3: collapse 8 barriers/tile to 2
// (only the two staging-safety certification points); one big straight-line
// read+MFMA block per tile so compiler overlaps LDS pipe with matrix pipe;
// running global pointers kill per-tile 64-bit staging address VALU.

#define M_DIM 8192
#define K_DIM 4096
#define N_DIM 16384

#define BM 256
#define BN 256
#define BK 64
#define NT (K_DIM / BK)          // 64 K-tiles
#define NWG ((M_DIM / BM) * (N_DIM / BN))   // 32*64 = 2048 blocks

typedef unsigned short u16;
typedef __attribute__((ext_vector_type(8))) short short8;   // 8 x bf16 bits
typedef __attribute__((ext_vector_type(4))) float floatx4;  // MFMA acc

__device__ __forceinline__ u16 f2bf(float f) {
    unsigned int u = __builtin_bit_cast(unsigned int, f);
    u += 0x7fffu + ((u >> 16) & 1u);
    return (u16)(u >> 16);
}

// ---------------- prep 1: x fp32 -> bf16 (verified) ----------------
__global__ __launch_bounds__(256) void cvt_x_kernel(const float4* __restrict__ x,
                                                    uint4* __restrict__ out) {
    int i = blockIdx.x * 256 + threadIdx.x;
    float4 a = x[2 * i];
    float4 b = x[2 * i + 1];
    uint4 o;
    o.x = (unsigned)f2bf(a.x) | ((unsigned)f2bf(a.y) << 16);
    o.y = (unsigned)f2bf(a.z) | ((unsigned)f2bf(a.w) << 16);
    o.z = (unsigned)f2bf(b.x) | ((unsigned)f2bf(b.y) << 16);
    o.w = (unsigned)f2bf(b.z) | ((unsigned)f2bf(b.w) << 16);
    out[i] = o;
}

// ---------------- prep 2: w_q[K,N] int32 -> wT[N,K] bf16 (verified) ----
__global__ __launch_bounds__(256) void transpose_wq(const int* __restrict__ wq,
                                                    u16* __restrict__ wT) {
    __shared__ u16 tile[64][65];
    const int n0 = blockIdx.x * 64;
    const int k0 = blockIdx.y * 64;
    const int tx = threadIdx.x;
    const int ty = threadIdx.y;
    #pragma unroll
    for (int r = 0; r < 4; ++r) {
        int kl = ty + 16 * r;
        const int4 v = *(const int4*)(wq + (size_t)(k0 + kl) * N_DIM + n0 + tx * 4);
        tile[kl][tx * 4 + 0] = f2bf((float)v.x);
        tile[kl][tx * 4 + 1] = f2bf((float)v.y);
        tile[kl][tx * 4 + 2] = f2bf((float)v.z);
        tile[kl][tx * 4 + 3] = f2bf((float)v.w);
    }
    __syncthreads();
    #pragma unroll
    for (int r = 0; r < 4; ++r) {
        int nl = ty + 16 * r;
        ushort4 o;
        o.x = tile[tx * 4 + 0][nl];
        o.y = tile[tx * 4 + 1][nl];
        o.z = tile[tx * 4 + 2][nl];
        o.w = tile[tx * 4 + 3][nl];
        *(ushort4*)(wT + (size_t)(n0 + nl) * K_DIM + k0 + tx * 4) = o;
    }
}

// ---------------- async global->LDS 16B ----------------
__device__ __forceinline__ void async_copy16(const u16* gptr, u16* ldsptr) {
    __builtin_amdgcn_global_load_lds(
        (const __attribute__((address_space(1))) void*)gptr,
        (__attribute__((address_space(3))) void*)ldsptr,
        16, 0, 0);
}

// ---------------- main GEMM: 256x256 tile, 2-barrier/tile schedule ---------
// LDS map (u16 units): buf p in {0,1} at p*32768.
//   A halves: p*32768 + h*8192          (h = row/128), [128][64] each
//   B halves: p*32768 + 16384 + h*8192
// XOR swizzle: 16B-slot s of row r stored at slot s^(r&7) (applied on the
// GLOBAL source address; LDS dest stays linear for global_load_lds), and the
// same XOR applied on the ds_read side. 16-way bank conflict -> 2-way (free).
//
// Barrier/staging invariants (per tile t, p = t&1, pn = p^1):
//  - tile-start barrier certifies: A(t)+B(t) landed in buf p (vmcnt(4) at end
//    of t-1) AND all reads of buf pn (tile t-1 data) were consumed by MFMAs.
//    -> STAGE_A(t+1)->pn legal right after it.
//  - mid barrier certifies: all B(t) registers consumed by MFMA (M1/M2 use
//    b0, M3 uses b1) -> STAGE_B(t+2)->p (B region) legal after it. The final
//    16 MFMAs (M4) reuse b1 REGISTERS only, and a1-kk1 reads target the A
//    region of buf p, which is only overwritten after the NEXT tile-start
//    barrier -> safe.
__global__ __launch_bounds__(512, 2) void gemm_bf16(const u16* __restrict__ A,
                                                    const u16* __restrict__ Bt,
                                                    const float* __restrict__ scale,
                                                    const float* __restrict__ bias,
                                                    float* __restrict__ C) {
    __shared__ u16 smem[65536];  // 128 KiB

    const int tid  = threadIdx.x;
    const int lane = tid & 63;
    const int wave = tid >> 6;
    const int wr   = wave >> 2;      // 0..1 : wave row (128 rows each)
    const int wc   = wave & 3;       // 0..3 : wave col (64 cols each)
    const int fr   = lane & 15;
    const int quad = lane >> 4;

    // T1: bijective XCD swizzle (2048 % 8 == 0) + GROUP_M=8 decomposition
    int wg = blockIdx.x;
    wg = (wg & 7) * (NWG / 8) + (wg >> 3);
    const int grp = wg >> 9;                 // / (8*64)
    const int rem = wg & 511;
    const int by  = grp * 8 + (rem & 7);     // 0..31
    const int bx  = rem >> 3;                // 0..63
    const int m0 = by * BM;
    const int n0 = bx * BN;

    // fragment-read offsets (u16): row (i*16+fr) within half, k-slot swizzled
    const int sw   = fr & 7;
    const int sl0  = (quad ^ sw) * 8;        // kk=0 16B-slot, swizzled
    const int sl1  = sl0 ^ 32;               // kk=1 slot
    const int rA   = fr * 64;
    const int aBase0 = wr * 8192;                                  // wave's A half
    const int bBase0 = 16384 + (wc >> 1) * 8192 + (wc & 1) * 4096; // B half + sub

    // staging coords: thread stages 16B chunks; rows srow + r*64, r=0..3
    const int srow  = tid >> 3;                        // 0..63
    const int sslot = ((tid & 7) ^ (srow & 7)) * 8;    // inverse-swizzled src slot
    const int ldst  = tid * 8;                         // linear LDS dest (u16)

    // running staging pointers (incremented by BK per tile; no per-tile 64-bit math)
    const u16* gA = A  + (size_t)(m0 + srow) * K_DIM + sslot + BK;      // A(t+1)
    const u16* gB = Bt + (size_t)(n0 + srow) * K_DIM + sslot + 2 * BK;  // B(t+2)

    floatx4 acc[8][4];
    #pragma unroll
    for (int i = 0; i < 8; ++i)
        #pragma unroll
        for (int j = 0; j < 4; ++j)
            acc[i][j] = (floatx4){0.f, 0.f, 0.f, 0.f};

    // prologue: stage A(0)+B(0)->buf0, B(1)->buf1.  queue: [A0x4, B0x4, B1x4]
    {
        const u16* a0 = A  + (size_t)(m0 + srow) * K_DIM + sslot;
        const u16* b0 = Bt + (size_t)(n0 + srow) * K_DIM + sslot;
        #pragma unroll
        for (int r = 0; r < 4; ++r)
            async_copy16(a0 + (size_t)(64 * r) * K_DIM, smem + ldst + r * 4096);
        #pragma unroll
        for (int r = 0; r < 4; ++r)
            async_copy16(b0 + (size_t)(64 * r) * K_DIM, smem + 16384 + ldst + r * 4096);
        #pragma unroll
        for (int r = 0; r < 4; ++r)
            async_copy16(b0 + BK + (size_t)(64 * r) * K_DIM,
                         smem + 32768 + 16384 + ldst + r * 4096);
    }
    asm volatile("s_waitcnt vmcnt(4)" ::: "memory");   // A0,B0 landed; B1 in flight
    __builtin_amdgcn_sched_barrier(0);
    __builtin_amdgcn_s_barrier();
    __builtin_amdgcn_sched_barrier(0);

    for (int t = 0; t < NT; ++t) {
        const int p     = t & 1;
        const int pOff  = p << 15;           // p * 32768
        const int pnOff = pOff ^ 32768;
        const u16* SA = smem + pOff + aBase0;
        const u16* SB = smem + pOff + bBase0;

        // ---- stage A(t+1) -> buf pn (legal per tile-start barrier) ----
        if (t + 1 < NT) {
            u16* d = smem + pnOff + ldst;
            #pragma unroll
            for (int r = 0; r < 4; ++r)
                async_copy16(gA + (size_t)(64 * r) * K_DIM, d + r * 4096);
        }
        gA += BK;

        // ---- big straight-line block: 20 ds_reads + 48 MFMA, compiler-scheduled
        short8 a0[4], a1[4], b0[4], b1[4];
        #pragma unroll
        for (int i = 0; i < 4; ++i)
            a0[i] = *(const short8*)(SA + i * 1024 + rA + sl0);
        #pragma unroll
        for (int j = 0; j < 4; ++j)
            b0[j] = *(const short8*)(SB + j * 1024 + rA + sl0);
        __builtin_amdgcn_s_setprio(1);
        #pragma unroll
        for (int i = 0; i < 4; ++i)
            #pragma unroll
            for (int j = 0; j < 4; ++j)
                acc[i][j] = __builtin_amdgcn_mfma_f32_16x16x32_bf16(a0[i], b0[j], acc[i][j], 0, 0, 0);
        __builtin_amdgcn_s_setprio(0);

        #pragma unroll
        for (int i = 0; i < 4; ++i)
            a1[i] = *(const short8*)(SA + (i + 4) * 1024 + rA + sl0);
        __builtin_amdgcn_s_setprio(1);
        #pragma unroll
        for (int i = 0; i < 4; ++i)
            #pragma unroll
            for (int j = 0; j < 4; ++j)
                acc[i + 4][j] = __builtin_amdgcn_mfma_f32_16x16x32_bf16(a1[i], b0[j], acc[i + 4][j], 0, 0, 0);
        __builtin_amdgcn_s_setprio(0);

        #pragma unroll
        for (int i = 0; i < 4; ++i)
            a0[i] = *(const short8*)(SA + i * 1024 + rA + sl1);
        #pragma unroll
        for (int j = 0; j < 4; ++j)
            b1[j] = *(const short8*)(SB + j * 1024 + rA + sl1);
        __builtin_amdgcn_s_setprio(1);
        #pragma unroll
        for (int i = 0; i < 4; ++i)
            #pragma unroll
            for (int j = 0; j < 4; ++j)
                acc[i][j] = __builtin_amdgcn_mfma_f32_16x16x32_bf16(a0[i], b1[j], acc[i][j], 0, 0, 0);
        __builtin_amdgcn_s_setprio(0);

        // pre-read A(i4-7, kk1) so M4 after the barrier is register-only
        #pragma unroll
        for (int i = 0; i < 4; ++i)
            a1[i] = *(const short8*)(SA + (i + 4) * 1024 + rA + sl1);

        // ---- mid barrier: all B(t) regs consumed -> B region of buf p free ----
        __builtin_amdgcn_sched_barrier(0);
        __builtin_amdgcn_s_barrier();
        __builtin_amdgcn_sched_barrier(0);

        if (t + 2 < NT) {
            u16* d = smem + pOff + 16384 + ldst;
            #pragma unroll
            for (int r = 0; r < 4; ++r)
                async_copy16(gB + (size_t)(64 * r) * K_DIM, d + r * 4096);
        }
        gB += BK;

        __builtin_amdgcn_s_setprio(1);
        #pragma unroll
        for (int i = 0; i < 4; ++i)
            #pragma unroll
            for (int j = 0; j < 4; ++j)
                acc[i + 4][j] = __builtin_amdgcn_mfma_f32_16x16x32_bf16(a1[i], b1[j], acc[i + 4][j], 0, 0, 0);
        __builtin_amdgcn_s_setprio(0);

        // retire tile t+1's loads; keep B(t+2) in flight
        if (t < NT - 2) {
            asm volatile("s_waitcnt vmcnt(4)" ::: "memory");
        } else if (t == NT - 2) {
            asm volatile("s_waitcnt vmcnt(0)" ::: "memory");
        }
        __builtin_amdgcn_sched_barrier(0);
        __builtin_amdgcn_s_barrier();
        __builtin_amdgcn_sched_barrier(0);
    }

    // epilogue: y = acc*scale[col] + bias[col]; C/D map col=lane&15, row=quad*4+r
    #pragma unroll
    for (int j = 0; j < 4; ++j) {
        const int col = n0 + wc * 64 + j * 16 + fr;
        const float s = scale[col];
        const float b = bias[col];
        #pragma unroll
        for (int i = 0; i < 8; ++i) {
            const int rowb = m0 + wr * 128 + i * 16 + quad * 4;
            #pragma unroll
            for (int r = 0; r < 4; ++r)
                C[(size_t)(rowb + r) * N_DIM + col] = acc[i][j][r] * s + b;
        }
    }
}

extern "C" void kernel_launch(void* const* d_in, const int* in_sizes, int n_in,
                              void* d_out, int out_size, void* d_ws, size_t ws_size,
                              hipStream_t stream) {
    const float* x     = (const float*)d_in[0];
    const int*   wq    = (const int*)d_in[1];
    const float* scale = (const float*)d_in[2];
    const float* bias  = (const float*)d_in[3];
    float* y = (float*)d_out;

    u16* wT = (u16*)d_ws;                                        // 128 MiB
    u16* xb = (u16*)((char*)d_ws + (size_t)N_DIM * K_DIM * 2);   // +64 MiB

    cvt_x_kernel<<<(M_DIM * (size_t)K_DIM) / (256 * 8), 256, 0, stream>>>(
        (const float4*)x, (uint4*)xb);
    transpose_wq<<<dim3(N_DIM / 64, K_DIM / 64), dim3(16, 16), 0, stream>>>(wq, wT);
    gemm_bf16<<<dim3(NWG), 512, 0, stream>>>(xb, wT, scale, bias, y);
}